// Round 7
// baseline (294.853 us; speedup 1.0000x reference)
//
#include <hip/hip_runtime.h>
#include <hip/hip_bf16.h>

typedef __bf16 bf16x8 __attribute__((ext_vector_type(8)));
typedef _Float16 f16x8 __attribute__((ext_vector_type(8)));
typedef unsigned short u16x8 __attribute__((ext_vector_type(8)));
typedef float f32x4 __attribute__((ext_vector_type(4)));
using bf16 = __hip_bfloat16;

constexpr int Cdim = 512;   // channels
constexpr int Nsp  = 4096;  // d*h*w
constexpr int NB   = 2;     // batch
constexpr float SCALE = 0.04419417382415922f;  // 512^-0.5
constexpr int EPITCH = 132; // epilogue LDS pitch (elems): 66 dw == 2 mod 32 -> quad rows 8 banks apart

// async 16B global->LDS (m97 pattern). LDS dest must be wave-uniform base + lane*16.
#define GL2LDS(gaddr, laddr)                                                              \
    __builtin_amdgcn_global_load_lds((const __attribute__((address_space(1))) void*)(gaddr), \
                                     (__attribute__((address_space(3))) void*)(laddr), 16, 0, 0)

// ---------------------------------------------------------------- weights fp32 -> bf16 + zero lsum, one launch
__global__ __launch_bounds__(256) void k_cvt_all(const float* __restrict__ wq, const float* __restrict__ wk,
                                                 const float* __restrict__ wv, const float* __restrict__ wo,
                                                 bf16* __restrict__ wqkb, bf16* __restrict__ wvb,
                                                 bf16* __restrict__ wob, float* __restrict__ lsum) {
    if (blockIdx.x >= 256) {  // zero 8192-float lsum
        #pragma unroll
        for (int j = 0; j < 8; ++j)
            ((float4*)lsum)[8 * threadIdx.x + j] = float4{0.f, 0.f, 0.f, 0.f};
        return;
    }
    int i = blockIdx.x * 256 + threadIdx.x;  // 65536 float4 groups per weight
    float4 q = ((const float4*)wq)[i];
    float4 k = ((const float4*)wk)[i];
    float4 v = ((const float4*)wv)[i];
    float4 o = ((const float4*)wo)[i];
    bf16* dq = wqkb + (size_t)i * 4;
    dq[0] = __float2bfloat16(q.x); dq[1] = __float2bfloat16(q.y);
    dq[2] = __float2bfloat16(q.z); dq[3] = __float2bfloat16(q.w);
    bf16* dk = wqkb + 262144 + (size_t)i * 4;
    dk[0] = __float2bfloat16(k.x); dk[1] = __float2bfloat16(k.y);
    dk[2] = __float2bfloat16(k.z); dk[3] = __float2bfloat16(k.w);
    bf16* dv = wvb + (size_t)i * 4;
    dv[0] = __float2bfloat16(v.x); dv[1] = __float2bfloat16(v.y);
    dv[2] = __float2bfloat16(v.z); dv[3] = __float2bfloat16(v.w);
    bf16* dw = wob + (size_t)i * 4;
    dw[0] = __float2bfloat16(o.x); dw[1] = __float2bfloat16(o.y);
    dw[2] = __float2bfloat16(o.z); dw[3] = __float2bfloat16(o.w);
}

// ---------------------------------------------------------------- groupnorm stats
__global__ __launch_bounds__(256) void k_gn_stats(const float* __restrict__ x, float* __restrict__ stats) {
    int bg = blockIdx.x;  // 0..63
    const float4* p = (const float4*)(x + (size_t)bg * (16 * 4096));
    float s = 0.f, s2 = 0.f;
    for (int i = threadIdx.x; i < 16384; i += 256) {
        float4 v = p[i];
        s  += v.x + v.y + v.z + v.w;
        s2 += v.x * v.x + v.y * v.y + v.z * v.z + v.w * v.w;
    }
    #pragma unroll
    for (int off = 32; off; off >>= 1) { s += __shfl_xor(s, off); s2 += __shfl_xor(s2, off); }
    __shared__ float rs[4], rs2[4];
    int w = threadIdx.x >> 6;
    if ((threadIdx.x & 63) == 0) { rs[w] = s; rs2[w] = s2; }
    __syncthreads();
    if (threadIdx.x == 0) {
        float S = rs[0] + rs[1] + rs[2] + rs[3];
        float S2 = rs2[0] + rs2[1] + rs2[2] + rs2[3];
        float mean = S * (1.f / 65536.f);
        float var  = S2 * (1.f / 65536.f) - mean * mean;
        stats[bg * 2]     = mean;
        stats[bg * 2 + 1] = rsqrtf(var + 1e-6f);
    }
}

// ---------------------------------------------------------------- groupnorm apply + transpose -> ht[b,n,c] bf16
__global__ __launch_bounds__(256) void k_gn_apply(const float* __restrict__ x, const float* __restrict__ stats,
                                                  const float* __restrict__ gamma, const float* __restrict__ beta,
                                                  bf16* __restrict__ ht) {
    int b = blockIdx.y;
    int n0 = blockIdx.x * 64;
    int tid = threadIdx.x;
    __shared__ float tile[64][65];
    int nn_l = tid & 63, cc0 = tid >> 6;
    int cc_w = tid & 63, nn0 = tid >> 6;
    for (int c0 = 0; c0 < Cdim; c0 += 64) {
        #pragma unroll
        for (int p = 0; p < 16; ++p) {
            int cc = p * 4 + cc0;
            tile[cc][nn_l] = x[(size_t)(b * Cdim + c0 + cc) * Nsp + n0 + nn_l];
        }
        __syncthreads();
        int c = c0 + cc_w, g = c >> 4;
        float mean = stats[(b * 32 + g) * 2];
        float rstd = stats[(b * 32 + g) * 2 + 1];
        float ga = gamma[c], be = beta[c];
        #pragma unroll
        for (int p = 0; p < 16; ++p) {
            int nn = p * 4 + nn0;
            float v = tile[cc_w][nn];
            ht[(size_t)(b * Nsp + n0 + nn) * Cdim + c] = __float2bfloat16((v - mean) * rstd * ga + be);
        }
        __syncthreads();
    }
}

// ---------------------------------------------------------------- MFMA dtype dispatch
template <int DT>
__device__ __forceinline__ f32x4 mma16(u16x8 a, u16x8 b, f32x4 c) {
    if constexpr (DT == 0)
        return __builtin_amdgcn_mfma_f32_16x16x32_bf16(__builtin_bit_cast(bf16x8, a),
                                                       __builtin_bit_cast(bf16x8, b), c, 0, 0, 0);
    else
        return __builtin_amdgcn_mfma_f32_16x16x32_f16(__builtin_bit_cast(f16x8, a),
                                                      __builtin_bit_cast(f16x8, b), c, 0, 0, 0);
}

// ---------------------------------------------------------------- NT GEMM (m97 structure) + split-K + exp epilogue
// out[m][n] = sum_k A[m][k]*B[n][k] (+bias)(+resid). 2-byte operand dtypes, pitches lda/ldb.
// BM x 128 tile (BM=64: wave 32x64, acc 32 AGPR -> 4 waves/SIMD; BM=128: wave 64x64, 64 AGPR, 3 waves),
// BK=64, 4 waves 2x2, global_load_lds width-16 staging, unpadded LDS.
// 2-byte outputs (OUTT 0/1): LDS-transpose epilogue (pitch-132) -> 16B coalesced stores.
// DT: 0=bf16, 1=f16. OUTT: 0=bf16, 1=f16, 2=f32 (scalar epilogue, supports RESID).
// BIAS: 0=none, 1=row, 2=col, 3=fused QK (col<512: (v+bias)*SCALE, else v+bias2).
// EXPSUM: v=exp(v), row sums atomically accumulated into lsum[bt*Nsp+row] (OUTT=0, BIAS=0, SPLITK=1).
// SPLITK>1: blockIdx.z = ksl*NB + bt, K-chunk = K/SPLITK, out slab zz*Os (partials; BIAS/RESID 0).
template <int BM, int DT, int OUTT, int BIAS, int RESID, int SPLITK, int EXPSUM>
__global__ __launch_bounds__(256, 4) void k_gemm_nt(
    const void* __restrict__ Av, long long As, int lda,
    const void* __restrict__ Bv, long long Bs, int ldb,
    const float* __restrict__ bias, const float* __restrict__ bias2,
    const float* __restrict__ resid, long long Rs,
    float* __restrict__ lsum,
    void* __restrict__ outv, long long Os,
    int N, int K) {
    constexpr int MT = BM / 32;       // m-tiles per wave
    constexpr int SME_STAGE = (BM + 128) * 64;
    constexpr int SME_EPI   = BM * EPITCH;
    constexpr int SME = SME_STAGE > SME_EPI ? SME_STAGE : SME_EPI;
    const int bm = blockIdx.x, bn = blockIdx.y, zz = blockIdx.z;
    const int bt  = (SPLITK > 1) ? (zz % NB) : zz;
    const int ksl = (SPLITK > 1) ? (zz / NB) : 0;
    const int Kc = K / SPLITK;
    const int kbeg = ksl * Kc;
    const unsigned short* Ab = (const unsigned short*)Av + (size_t)bt * As;
    const unsigned short* Bb = (const unsigned short*)Bv + (size_t)bt * Bs;
    const int tid = threadIdx.x, lane = tid & 63, w = tid >> 6;
    const int quad = lane >> 4, l16 = lane & 15;
    const int wm = w >> 1, wn = w & 1;
    __shared__ __align__(16) unsigned short smem[SME];
    unsigned short (*Asub)[64] = (unsigned short(*)[64])smem;
    unsigned short (*Bsub)[64] = (unsigned short(*)[64])(smem + BM * 64);
    f32x4 zero4 = {0.f, 0.f, 0.f, 0.f};
    f32x4 acc[MT][4];
    #pragma unroll
    for (int i = 0; i < MT; ++i)
        #pragma unroll
        for (int j = 0; j < 4; ++j) acc[i][j] = zero4;
    const int row0 = bm * BM, col0 = bn * 128;
    const size_t ldab = (size_t)lda * 2, ldbb = (size_t)ldb * 2;
    for (int k0 = kbeg; k0 < kbeg + Kc; k0 += 64) {
        const char* Abase = (const char*)Ab + (size_t)k0 * 2;
        const char* Bbase = (const char*)Bb + (size_t)k0 * 2;
        #pragma unroll
        for (int p = 0; p < BM / 32; ++p) {
            int o = p * 4096 + tid * 16;         // byte offset into A LDS tile
            int r = o >> 7, ir = o & 127;        // row (128 B per row), byte-in-row
            GL2LDS(Abase + (size_t)(row0 + r) * ldab + ir, (char*)smem + o);
        }
        #pragma unroll
        for (int p = 0; p < 4; ++p) {
            int o = p * 4096 + tid * 16;
            int r = o >> 7, ir = o & 127;
            GL2LDS(Bbase + (size_t)(col0 + r) * ldbb + ir, (char*)smem + BM * 128 + o);
        }
        __syncthreads();
        #pragma unroll
        for (int ks = 0; ks < 2; ++ks) {
            u16x8 af[MT], bfr[4];
            #pragma unroll
            for (int t = 0; t < MT; ++t) af[t] = *(const u16x8*)&Asub[wm * (BM / 2) + t * 16 + l16][ks * 32 + quad * 8];
            #pragma unroll
            for (int t = 0; t < 4; ++t) bfr[t] = *(const u16x8*)&Bsub[wn * 64 + t * 16 + l16][ks * 32 + quad * 8];
            #pragma unroll
            for (int tm = 0; tm < MT; ++tm)
                #pragma unroll
                for (int tn = 0; tn < 4; ++tn) acc[tm][tn] = mma16<DT>(af[tm], bfr[tn], acc[tm][tn]);
        }
        __syncthreads();
    }

    if constexpr (OUTT == 2) {
        // scalar fp32 epilogue (final projection: bias + residual + fp32 out)
        #pragma unroll
        for (int tm = 0; tm < MT; ++tm)
            #pragma unroll
            for (int tn = 0; tn < 4; ++tn)
                #pragma unroll
                for (int r = 0; r < 4; ++r) {
                    int row = row0 + wm * (BM / 2) + tm * 16 + quad * 4 + r;
                    int col = col0 + wn * 64 + tn * 16 + l16;
                    float v = acc[tm][tn][r];
                    if constexpr (BIAS == 1) v += bias[row];
                    else if constexpr (BIAS == 2) v += bias[col];
                    if constexpr (RESID) v += resid[(size_t)bt * Rs + (size_t)row * N + col];
                    ((float*)outv)[(size_t)zz * Os + (size_t)row * N + col] = v;
                }
    } else {
        // ---- LDS-transpose epilogue (2-byte outputs) ----
        #pragma unroll
        for (int tn = 0; tn < 4; ++tn) {
            int colL = wn * 64 + tn * 16 + l16;
            float bc = 0.f;
            if constexpr (BIAS == 2) bc = bias[col0 + colL];
            else if constexpr (BIAS == 3) {
                int col = col0 + colL;
                bc = (col < 512) ? bias[col] : bias2[col - 512];
            }
            #pragma unroll
            for (int tm = 0; tm < MT; ++tm)
                #pragma unroll
                for (int r = 0; r < 4; ++r) {
                    int rowL = wm * (BM / 2) + tm * 16 + quad * 4 + r;
                    float v = acc[tm][tn][r];
                    if constexpr (BIAS == 1) v += bias[row0 + rowL];
                    else if constexpr (BIAS == 2) v += bc;
                    else if constexpr (BIAS == 3) {
                        int col = col0 + colL;
                        v = (col < 512) ? (v + bc) * SCALE : v + bc;
                    }
                    if constexpr (EXPSUM) v = __expf(v);
                    unsigned short hv;
                    if constexpr (OUTT == 1) { _Float16 h = (_Float16)v; hv = __builtin_bit_cast(unsigned short, h); }
                    else { bf16 h = __float2bfloat16(v); hv = __builtin_bit_cast(unsigned short, h); }
                    smem[rowL * EPITCH + colL] = hv;
                }
        }
        __syncthreads();
        // read phase: chunk = tid&15 (8 cols), rows (tid>>4)*(BM/16) + i; 16B coalesced stores
        const int cch = (tid & 15) * 8;
        const int rg  = (tid >> 4) * (BM / 16);
        #pragma unroll
        for (int i = 0; i < BM / 16; ++i) {
            int rowL = rg + i;
            u16x8 hv = *(const u16x8*)&smem[rowL * EPITCH + cch];
            *(u16x8*)((unsigned short*)outv + (size_t)zz * Os + (size_t)(row0 + rowL) * N + col0 + cch) = hv;
            if constexpr (EXPSUM) {
                float ps = 0.f;
                #pragma unroll
                for (int e = 0; e < 8; ++e) {
                    bf16 h = __builtin_bit_cast(bf16, hv[e]);
                    ps += __bfloat162float(h);
                }
                #pragma unroll
                for (int m = 1; m < 16; m <<= 1) ps += __shfl_xor(ps, m);
                if ((lane & 15) == 0) atomicAdd(lsum + (size_t)bt * Nsp + row0 + rowL, ps);
            }
        }
    }
}

// ---------------------------------------------------------------- sum 4 bf16 split-K partials, /l -> bf16
__global__ __launch_bounds__(256) void k_reduce4(const bf16* __restrict__ P, const float* __restrict__ lsum,
                                                 bf16* __restrict__ O) {
    constexpr size_t SL = (size_t)NB * Nsp * Cdim;  // 4194304 elems per split slab
    size_t i = ((size_t)blockIdx.x * 256 + threadIdx.x) * 8;
    float linv = 1.f / lsum[i >> 9];  // flat/512 = b*Nsp + row
    union { bf16 h[8]; uint4 u; } a, b, c, d, r;
    a.u = *(const uint4*)(P + i);
    b.u = *(const uint4*)(P + SL + i);
    c.u = *(const uint4*)(P + 2 * SL + i);
    d.u = *(const uint4*)(P + 3 * SL + i);
    #pragma unroll
    for (int e = 0; e < 8; ++e) {
        float s = __bfloat162float(a.h[e]) + __bfloat162float(b.h[e]) +
                  __bfloat162float(c.h[e]) + __bfloat162float(d.h[e]);
        r.h[e] = __float2bfloat16(s * linv);
    }
    *(uint4*)(O + i) = r.u;
}

// ---------------------------------------------------------------- launcher
extern "C" void kernel_launch(void* const* d_in, const int* in_sizes, int n_in,
                              void* d_out, int out_size, void* d_ws, size_t ws_size,
                              hipStream_t stream) {
    const float* x     = (const float*)d_in[0];
    const float* gamma = (const float*)d_in[1];
    const float* beta  = (const float*)d_in[2];
    const float* wq = (const float*)d_in[3];  const float* bq = (const float*)d_in[4];
    const float* wk = (const float*)d_in[5];  const float* bk = (const float*)d_in[6];
    const float* wv = (const float*)d_in[7];  const float* bv = (const float*)d_in[8];
    const float* wo = (const float*)d_in[9];  const float* bo = (const float*)d_in[10];
    float* out = (float*)d_out;

    // workspace layout (Opart aliases ht+QKt+pad, all dead by PV time)
    char* ws = (char*)d_ws;
    float* stats = (float*)ws;
    size_t off = 1024;
    float* lsum = (float*)(ws + off); off += (size_t)NB * Nsp * 4 + 1024;  // 32 KB row sums
    bf16* wqkb = (bf16*)(ws + off); off += (size_t)1024 * 512 * 2;        // 1 MB  [1024][512] Q then K
    bf16* wvb  = (bf16*)(ws + off); off += (size_t)512 * 512 * 2;         // 0.5 MB
    bf16* wob  = (bf16*)(ws + off); off += (size_t)512 * 512 * 2;         // 0.5 MB
    bf16* Vm   = (bf16*)(ws + off); off += (size_t)NB * Nsp * Cdim * 2;   // 8 MB  [b][c][j]
    bf16* Ot   = (bf16*)(ws + off); off += (size_t)NB * Nsp * Cdim * 2;   // 8 MB  [b][i][c]
    bf16* Sm   = (bf16*)(ws + off); off += (size_t)NB * Nsp * Nsp * 2;    // 64 MB [b][i][j] (S then P=exp)
    bf16* ht   = (bf16*)(ws + off); off += (size_t)NB * Nsp * Cdim * 2;   // 8 MB  [b][n][c]
    bf16* QKt  = (bf16*)(ws + off); off += (size_t)NB * Nsp * 1024 * 2;   // 16 MB [b][n][1024]
    off += (size_t)8 << 20;                                               // 8 MB pad for Opart
    bf16* Opart = (bf16*)ht;  // 32 MB: 4 slabs x [b][i][c], aliases ht+QKt+pad

    k_cvt_all<<<257, 256, 0, stream>>>(wq, wk, wv, wo, wqkb, wvb, wob, lsum);
    k_gn_stats<<<64, 256, 0, stream>>>(x, stats);
    k_gn_apply<<<dim3(64, 2), 256, 0, stream>>>(x, stats, gamma, beta, ht);

    const long long hs = (long long)Nsp * Cdim;    // 2097152
    const long long qs = (long long)Nsp * 1024;    // 4194304
    const long long ss = (long long)Nsp * Nsp;     // 16777216

    // fused Q+K proj: QKt[i][co'] = (sum_k ht[i][k] wqk[co'][k] + b) (*SCALE for Q half)
    k_gemm_nt<64, 0, 0, 3, 0, 1, 0><<<dim3(64, 8, 2), 256, 0, stream>>>(
        ht, hs, 512, wqkb, 0, 512, bq, bk, nullptr, 0, nullptr, QKt, qs, 1024, 512);
    // V: Vm[co][j] = sum_k wv[co][k] ht[j][k] + bv  (M=512, N=4096, bf16 out)
    k_gemm_nt<64, 0, 0, 1, 0, 1, 0><<<dim3(8, 32, 2), 256, 0, stream>>>(
        wvb, 0, 512, ht, hs, 512, bv, nullptr, nullptr, 0, nullptr, Vm, hs, 4096, 512);
    // S = Q K^T -> P = exp(S) bf16 + row sums (M=N=4096, K=512; logits pre-scaled)
    k_gemm_nt<64, 0, 0, 0, 0, 1, 1><<<dim3(64, 32, 2), 256, 0, stream>>>(
        QKt, qs, 1024, QKt + 512, qs, 1024, nullptr, nullptr, nullptr, 0, lsum, Sm, ss, 4096, 512);
    // O_unnorm = P V^T split-K=4: partials[ksl*2+bt][i][c]  (M=4096, N=512, K=4096, bf16)
    k_gemm_nt<64, 0, 0, 0, 0, 4, 0><<<dim3(64, 4, 8), 256, 0, stream>>>(
        Sm, ss, 4096, Vm, hs, 4096, nullptr, nullptr, nullptr, 0, nullptr, Opart, hs, 512, 4096);
    // reduce 4 partials, divide by row sums -> Ot bf16
    k_reduce4<<<4096, 256, 0, stream>>>(Opart, lsum, Ot);
    // out[co][i] = x[co][i] + bo[co] + sum_k wo[co][k] Ot[i][k]  (fp32 out + residual)
    k_gemm_nt<64, 0, 2, 1, 1, 1, 0><<<dim3(8, 32, 2), 256, 0, stream>>>(
        wob, 0, 512, Ot, hs, 512, bo, nullptr, x, hs, nullptr, out, hs, 4096, 512);
}

// Round 9
// 264.395 us; speedup vs baseline: 1.1152x; 1.1152x over previous
//
#include <hip/hip_runtime.h>
#include <hip/hip_bf16.h>

typedef __bf16 bf16x8 __attribute__((ext_vector_type(8)));
typedef _Float16 f16x8 __attribute__((ext_vector_type(8)));
typedef unsigned short u16x8 __attribute__((ext_vector_type(8)));
typedef float f32x4 __attribute__((ext_vector_type(4)));
using bf16 = __hip_bfloat16;

constexpr int Cdim = 512;   // channels
constexpr int Nsp  = 4096;  // d*h*w
constexpr int NB   = 2;     // batch
constexpr float SCALE = 0.04419417382415922f;  // 512^-0.5
constexpr int EPITCH = 132; // epilogue LDS pitch (elems)

// async 16B global->LDS (m97 pattern). LDS dest must be wave-uniform base + lane*16.
#define GL2LDS(gaddr, laddr)                                                              \
    __builtin_amdgcn_global_load_lds((const __attribute__((address_space(1))) void*)(gaddr), \
                                     (__attribute__((address_space(3))) void*)(laddr), 16, 0, 0)

// ---------------------------------------------------------------- weights fp32 -> bf16 + zero lsum, one launch
__global__ __launch_bounds__(256) void k_cvt_all(const float* __restrict__ wq, const float* __restrict__ wk,
                                                 const float* __restrict__ wv, const float* __restrict__ wo,
                                                 bf16* __restrict__ wqkb, bf16* __restrict__ wvb,
                                                 bf16* __restrict__ wob, float* __restrict__ lsum) {
    if (blockIdx.x >= 256) {  // zero 8192-float lsum
        #pragma unroll
        for (int j = 0; j < 8; ++j)
            ((float4*)lsum)[8 * threadIdx.x + j] = float4{0.f, 0.f, 0.f, 0.f};
        return;
    }
    int i = blockIdx.x * 256 + threadIdx.x;  // 65536 float4 groups per weight
    float4 q = ((const float4*)wq)[i];
    float4 k = ((const float4*)wk)[i];
    float4 v = ((const float4*)wv)[i];
    float4 o = ((const float4*)wo)[i];
    bf16* dq = wqkb + (size_t)i * 4;
    dq[0] = __float2bfloat16(q.x); dq[1] = __float2bfloat16(q.y);
    dq[2] = __float2bfloat16(q.z); dq[3] = __float2bfloat16(q.w);
    bf16* dk = wqkb + 262144 + (size_t)i * 4;
    dk[0] = __float2bfloat16(k.x); dk[1] = __float2bfloat16(k.y);
    dk[2] = __float2bfloat16(k.z); dk[3] = __float2bfloat16(k.w);
    bf16* dv = wvb + (size_t)i * 4;
    dv[0] = __float2bfloat16(v.x); dv[1] = __float2bfloat16(v.y);
    dv[2] = __float2bfloat16(v.z); dv[3] = __float2bfloat16(v.w);
    bf16* dw = wob + (size_t)i * 4;
    dw[0] = __float2bfloat16(o.x); dw[1] = __float2bfloat16(o.y);
    dw[2] = __float2bfloat16(o.z); dw[3] = __float2bfloat16(o.w);
}

// ---------------------------------------------------------------- groupnorm stats
__global__ __launch_bounds__(256) void k_gn_stats(const float* __restrict__ x, float* __restrict__ stats) {
    int bg = blockIdx.x;  // 0..63
    const float4* p = (const float4*)(x + (size_t)bg * (16 * 4096));
    float s = 0.f, s2 = 0.f;
    for (int i = threadIdx.x; i < 16384; i += 256) {
        float4 v = p[i];
        s  += v.x + v.y + v.z + v.w;
        s2 += v.x * v.x + v.y * v.y + v.z * v.z + v.w * v.w;
    }
    #pragma unroll
    for (int off = 32; off; off >>= 1) { s += __shfl_xor(s, off); s2 += __shfl_xor(s2, off); }
    __shared__ float rs[4], rs2[4];
    int w = threadIdx.x >> 6;
    if ((threadIdx.x & 63) == 0) { rs[w] = s; rs2[w] = s2; }
    __syncthreads();
    if (threadIdx.x == 0) {
        float S = rs[0] + rs[1] + rs[2] + rs[3];
        float S2 = rs2[0] + rs2[1] + rs2[2] + rs2[3];
        float mean = S * (1.f / 65536.f);
        float var  = S2 * (1.f / 65536.f) - mean * mean;
        stats[bg * 2]     = mean;
        stats[bg * 2 + 1] = rsqrtf(var + 1e-6f);
    }
}

// ---------------------------------------------------------------- groupnorm apply + transpose -> ht[b,n,c] bf16
__global__ __launch_bounds__(256) void k_gn_apply(const float* __restrict__ x, const float* __restrict__ stats,
                                                  const float* __restrict__ gamma, const float* __restrict__ beta,
                                                  bf16* __restrict__ ht) {
    int b = blockIdx.y;
    int n0 = blockIdx.x * 64;
    int tid = threadIdx.x;
    __shared__ float tile[64][65];
    int nn_l = tid & 63, cc0 = tid >> 6;
    int cc_w = tid & 63, nn0 = tid >> 6;
    for (int c0 = 0; c0 < Cdim; c0 += 64) {
        #pragma unroll
        for (int p = 0; p < 16; ++p) {
            int cc = p * 4 + cc0;
            tile[cc][nn_l] = x[(size_t)(b * Cdim + c0 + cc) * Nsp + n0 + nn_l];
        }
        __syncthreads();
        int c = c0 + cc_w, g = c >> 4;
        float mean = stats[(b * 32 + g) * 2];
        float rstd = stats[(b * 32 + g) * 2 + 1];
        float ga = gamma[c], be = beta[c];
        #pragma unroll
        for (int p = 0; p < 16; ++p) {
            int nn = p * 4 + nn0;
            float v = tile[cc_w][nn];
            ht[(size_t)(b * Nsp + n0 + nn) * Cdim + c] = __float2bfloat16((v - mean) * rstd * ga + be);
        }
        __syncthreads();
    }
}

// ---------------------------------------------------------------- MFMA dtype dispatch
template <int DT>
__device__ __forceinline__ f32x4 mma16(u16x8 a, u16x8 b, f32x4 c) {
    if constexpr (DT == 0)
        return __builtin_amdgcn_mfma_f32_16x16x32_bf16(__builtin_bit_cast(bf16x8, a),
                                                       __builtin_bit_cast(bf16x8, b), c, 0, 0, 0);
    else
        return __builtin_amdgcn_mfma_f32_16x16x32_f16(__builtin_bit_cast(f16x8, a),
                                                      __builtin_bit_cast(f16x8, b), c, 0, 0, 0);
}

// ---------------------------------------------------------------- NT GEMM (m97 structure) + XOR-swizzled LDS
// out[m][n] = sum_k A[m][k]*B[n][k] (+bias)(+resid). 2-byte operand dtypes, pitches lda/ldb.
// BM x 128 tile, BK=64, 4 waves 2x2, global_load_lds width-16 staging.
// LDS layout is XOR-swizzled: stored[r][c] = global[r][c ^ (r&7)] (c = 16B chunk, 8/row).
// A quad's 16 lanes then read 8 distinct chunks x 2 rows -> 2-way (free) instead of 16-way conflicts.
// 2-byte outputs (OUTT 0/1): LDS-transpose epilogue (pitch-132) -> 16B coalesced stores.
// DT: 0=bf16, 1=f16. OUTT: 0=bf16, 1=f16, 2=f32 (scalar epilogue, supports RESID).
// BIAS: 0=none, 1=row, 2=col, 3=fused QK (col<512: (v+bias)*SCALE, else v+bias2).
// EXPSUM: v=exp(v), row sums atomically accumulated into lsum[bt*Nsp+row] (OUTT=0, BIAS=0, SPLITK=1).
// SPLITK>1: blockIdx.z = ksl*NB + bt, K-chunk = K/SPLITK, out slab zz*Os (partials; BIAS/RESID 0).
template <int BM, int DT, int OUTT, int BIAS, int RESID, int SPLITK, int EXPSUM>
__global__ __launch_bounds__(256) void k_gemm_nt(
    const void* __restrict__ Av, long long As, int lda,
    const void* __restrict__ Bv, long long Bs, int ldb,
    const float* __restrict__ bias, const float* __restrict__ bias2,
    const float* __restrict__ resid, long long Rs,
    float* __restrict__ lsum,
    void* __restrict__ outv, long long Os,
    int N, int K) {
    constexpr int MT = BM / 32;       // m-tiles per wave
    constexpr int SME_STAGE = (BM + 128) * 64;
    constexpr int SME_EPI   = BM * EPITCH;
    constexpr int SME = SME_STAGE > SME_EPI ? SME_STAGE : SME_EPI;
    const int bm = blockIdx.x, bn = blockIdx.y, zz = blockIdx.z;
    const int bt  = (SPLITK > 1) ? (zz % NB) : zz;
    const int ksl = (SPLITK > 1) ? (zz / NB) : 0;
    const int Kc = K / SPLITK;
    const int kbeg = ksl * Kc;
    const unsigned short* Ab = (const unsigned short*)Av + (size_t)bt * As;
    const unsigned short* Bb = (const unsigned short*)Bv + (size_t)bt * Bs;
    const int tid = threadIdx.x, lane = tid & 63, w = tid >> 6;
    const int quad = lane >> 4, l16 = lane & 15;
    const int wm = w >> 1, wn = w & 1;
    __shared__ __align__(16) unsigned short smem[SME];
    unsigned short (*Asub)[64] = (unsigned short(*)[64])smem;
    unsigned short (*Bsub)[64] = (unsigned short(*)[64])(smem + BM * 64);
    f32x4 zero4 = {0.f, 0.f, 0.f, 0.f};
    f32x4 acc[MT][4];
    #pragma unroll
    for (int i = 0; i < MT; ++i)
        #pragma unroll
        for (int j = 0; j < 4; ++j) acc[i][j] = zero4;
    const int row0 = bm * BM, col0 = bn * 128;
    const size_t ldab = (size_t)lda * 2, ldbb = (size_t)ldb * 2;
    const int lsw = (l16 & 7) * 8;  // fragment-read swizzle (elems)
    for (int k0 = kbeg; k0 < kbeg + Kc; k0 += 64) {
        const char* Abase = (const char*)Ab + (size_t)k0 * 2;
        const char* Bbase = (const char*)Bb + (size_t)k0 * 2;
        #pragma unroll
        for (int p = 0; p < BM / 32; ++p) {
            int o = p * 4096 + tid * 16;         // byte offset into A LDS tile
            int r = o >> 7;                      // row (128 B per row)
            int cs = ((o >> 4) ^ r) & 7;         // swizzled source chunk
            GL2LDS(Abase + (size_t)(row0 + r) * ldab + cs * 16, (char*)smem + o);
        }
        #pragma unroll
        for (int p = 0; p < 4; ++p) {
            int o = p * 4096 + tid * 16;
            int r = o >> 7;
            int cs = ((o >> 4) ^ r) & 7;
            GL2LDS(Bbase + (size_t)(col0 + r) * ldbb + cs * 16, (char*)smem + BM * 128 + o);
        }
        __syncthreads();
        #pragma unroll
        for (int ks = 0; ks < 2; ++ks) {
            u16x8 af[MT], bfr[4];
            #pragma unroll
            for (int t = 0; t < MT; ++t)
                af[t] = *(const u16x8*)&Asub[wm * (BM / 2) + t * 16 + l16][(ks * 32 + quad * 8) ^ lsw];
            #pragma unroll
            for (int t = 0; t < 4; ++t)
                bfr[t] = *(const u16x8*)&Bsub[wn * 64 + t * 16 + l16][(ks * 32 + quad * 8) ^ lsw];
            #pragma unroll
            for (int tm = 0; tm < MT; ++tm)
                #pragma unroll
                for (int tn = 0; tn < 4; ++tn) acc[tm][tn] = mma16<DT>(af[tm], bfr[tn], acc[tm][tn]);
        }
        __syncthreads();
    }

    if constexpr (OUTT == 2) {
        // scalar fp32 epilogue (final projection: bias + residual + fp32 out)
        #pragma unroll
        for (int tm = 0; tm < MT; ++tm)
            #pragma unroll
            for (int tn = 0; tn < 4; ++tn)
                #pragma unroll
                for (int r = 0; r < 4; ++r) {
                    int row = row0 + wm * (BM / 2) + tm * 16 + quad * 4 + r;
                    int col = col0 + wn * 64 + tn * 16 + l16;
                    float v = acc[tm][tn][r];
                    if constexpr (BIAS == 1) v += bias[row];
                    else if constexpr (BIAS == 2) v += bias[col];
                    if constexpr (RESID) v += resid[(size_t)bt * Rs + (size_t)row * N + col];
                    ((float*)outv)[(size_t)zz * Os + (size_t)row * N + col] = v;
                }
    } else {
        // ---- LDS-transpose epilogue (2-byte outputs) ----
        #pragma unroll
        for (int tn = 0; tn < 4; ++tn) {
            int colL = wn * 64 + tn * 16 + l16;
            float bc = 0.f;
            if constexpr (BIAS == 2) bc = bias[col0 + colL];
            else if constexpr (BIAS == 3) {
                int col = col0 + colL;
                bc = (col < 512) ? bias[col] : bias2[col - 512];
            }
            #pragma unroll
            for (int tm = 0; tm < MT; ++tm)
                #pragma unroll
                for (int r = 0; r < 4; ++r) {
                    int rowL = wm * (BM / 2) + tm * 16 + quad * 4 + r;
                    float v = acc[tm][tn][r];
                    if constexpr (BIAS == 1) v += bias[row0 + rowL];
                    else if constexpr (BIAS == 2) v += bc;
                    else if constexpr (BIAS == 3) {
                        int col = col0 + colL;
                        v = (col < 512) ? (v + bc) * SCALE : v + bc;
                    }
                    if constexpr (EXPSUM) v = __expf(v);
                    unsigned short hv;
                    if constexpr (OUTT == 1) { _Float16 h = (_Float16)v; hv = __builtin_bit_cast(unsigned short, h); }
                    else { bf16 h = __float2bfloat16(v); hv = __builtin_bit_cast(unsigned short, h); }
                    smem[rowL * EPITCH + colL] = hv;
                }
        }
        __syncthreads();
        // read phase: chunk = tid&15 (8 cols), rows (tid>>4)*(BM/16) + i; 16B coalesced stores
        const int cch = (tid & 15) * 8;
        const int rg  = (tid >> 4) * (BM / 16);
        #pragma unroll
        for (int i = 0; i < BM / 16; ++i) {
            int rowL = rg + i;
            u16x8 hv = *(const u16x8*)&smem[rowL * EPITCH + cch];
            *(u16x8*)((unsigned short*)outv + (size_t)zz * Os + (size_t)(row0 + rowL) * N + col0 + cch) = hv;
            if constexpr (EXPSUM) {
                float ps = 0.f;
                #pragma unroll
                for (int e = 0; e < 8; ++e) {
                    bf16 h = __builtin_bit_cast(bf16, hv[e]);
                    ps += __bfloat162float(h);
                }
                #pragma unroll
                for (int m = 1; m < 16; m <<= 1) ps += __shfl_xor(ps, m);
                if ((lane & 15) == 0) atomicAdd(lsum + (size_t)bt * Nsp + row0 + rowL, ps);
            }
        }
    }
}

// ---------------------------------------------------------------- sum 4 bf16 split-K partials, /l -> bf16
__global__ __launch_bounds__(256) void k_reduce4(const bf16* __restrict__ P, const float* __restrict__ lsum,
                                                 bf16* __restrict__ O) {
    constexpr size_t SL = (size_t)NB * Nsp * Cdim;  // 4194304 elems per split slab
    size_t i = ((size_t)blockIdx.x * 256 + threadIdx.x) * 8;
    float linv = 1.f / lsum[i >> 9];  // flat/512 = b*Nsp + row
    union { bf16 h[8]; uint4 u; } a, b, c, d, r;
    a.u = *(const uint4*)(P + i);
    b.u = *(const uint4*)(P + SL + i);
    c.u = *(const uint4*)(P + 2 * SL + i);
    d.u = *(const uint4*)(P + 3 * SL + i);
    #pragma unroll
    for (int e = 0; e < 8; ++e) {
        float s = __bfloat162float(a.h[e]) + __bfloat162float(b.h[e]) +
                  __bfloat162float(c.h[e]) + __bfloat162float(d.h[e]);
        r.h[e] = __float2bfloat16(s * linv);
    }
    *(uint4*)(O + i) = r.u;
}

// ---------------------------------------------------------------- launcher
extern "C" void kernel_launch(void* const* d_in, const int* in_sizes, int n_in,
                              void* d_out, int out_size, void* d_ws, size_t ws_size,
                              hipStream_t stream) {
    const float* x     = (const float*)d_in[0];
    const float* gamma = (const float*)d_in[1];
    const float* beta  = (const float*)d_in[2];
    const float* wq = (const float*)d_in[3];  const float* bq = (const float*)d_in[4];
    const float* wk = (const float*)d_in[5];  const float* bk = (const float*)d_in[6];
    const float* wv = (const float*)d_in[7];  const float* bv = (const float*)d_in[8];
    const float* wo = (const float*)d_in[9];  const float* bo = (const float*)d_in[10];
    float* out = (float*)d_out;

    // workspace layout (Opart aliases ht+QKt+pad, all dead by PV time)
    char* ws = (char*)d_ws;
    float* stats = (float*)ws;
    size_t off = 1024;
    float* lsum = (float*)(ws + off); off += (size_t)NB * Nsp * 4 + 1024;  // 32 KB row sums
    bf16* wqkb = (bf16*)(ws + off); off += (size_t)1024 * 512 * 2;        // 1 MB  [1024][512] Q then K
    bf16* wvb  = (bf16*)(ws + off); off += (size_t)512 * 512 * 2;         // 0.5 MB
    bf16* wob  = (bf16*)(ws + off); off += (size_t)512 * 512 * 2;         // 0.5 MB
    bf16* Vm   = (bf16*)(ws + off); off += (size_t)NB * Nsp * Cdim * 2;   // 8 MB  [b][c][j]
    bf16* Ot   = (bf16*)(ws + off); off += (size_t)NB * Nsp * Cdim * 2;   // 8 MB  [b][i][c]
    bf16* Sm   = (bf16*)(ws + off); off += (size_t)NB * Nsp * Nsp * 2;    // 64 MB [b][i][j] (S then P=exp)
    bf16* ht   = (bf16*)(ws + off); off += (size_t)NB * Nsp * Cdim * 2;   // 8 MB  [b][n][c]
    bf16* QKt  = (bf16*)(ws + off); off += (size_t)NB * Nsp * 1024 * 2;   // 16 MB [b][n][1024]
    off += (size_t)8 << 20;                                               // 8 MB pad for Opart
    bf16* Opart = (bf16*)ht;  // 32 MB: 4 slabs x [b][i][c], aliases ht+QKt+pad

    k_cvt_all<<<257, 256, 0, stream>>>(wq, wk, wv, wo, wqkb, wvb, wob, lsum);
    k_gn_stats<<<64, 256, 0, stream>>>(x, stats);
    k_gn_apply<<<dim3(64, 2), 256, 0, stream>>>(x, stats, gamma, beta, ht);

    const long long hs = (long long)Nsp * Cdim;    // 2097152
    const long long qs = (long long)Nsp * 1024;    // 4194304
    const long long ss = (long long)Nsp * Nsp;     // 16777216

    // fused Q+K proj: QKt[i][co'] = (sum_k ht[i][k] wqk[co'][k] + b) (*SCALE for Q half)
    k_gemm_nt<128, 0, 0, 3, 0, 1, 0><<<dim3(32, 8, 2), 256, 0, stream>>>(
        ht, hs, 512, wqkb, 0, 512, bq, bk, nullptr, 0, nullptr, QKt, qs, 1024, 512);
    // V: Vm[co][j] = sum_k wv[co][k] ht[j][k] + bv  (M=512, N=4096, bf16 out)
    k_gemm_nt<128, 0, 0, 1, 0, 1, 0><<<dim3(4, 32, 2), 256, 0, stream>>>(
        wvb, 0, 512, ht, hs, 512, bv, nullptr, nullptr, 0, nullptr, Vm, hs, 4096, 512);
    // S = Q K^T -> P = exp(S) bf16 + row sums (M=N=4096, K=512; logits pre-scaled)
    k_gemm_nt<128, 0, 0, 0, 0, 1, 1><<<dim3(32, 32, 2), 256, 0, stream>>>(
        QKt, qs, 1024, QKt + 512, qs, 1024, nullptr, nullptr, nullptr, 0, lsum, Sm, ss, 4096, 512);
    // O_unnorm = P V^T split-K=4: partials[ksl*2+bt][i][c]  (M=4096, N=512, K=4096, bf16)
    k_gemm_nt<128, 0, 0, 0, 0, 4, 0><<<dim3(32, 4, 8), 256, 0, stream>>>(
        Sm, ss, 4096, Vm, hs, 4096, nullptr, nullptr, nullptr, 0, nullptr, Opart, hs, 512, 4096);
    // reduce 4 partials, divide by row sums -> Ot bf16
    k_reduce4<<<4096, 256, 0, stream>>>(Opart, lsum, Ot);
    // out[co][i] = x[co][i] + bo[co] + sum_k wo[co][k] Ot[i][k]  (fp32 out + residual)
    k_gemm_nt<128, 0, 2, 1, 1, 1, 0><<<dim3(4, 32, 2), 256, 0, stream>>>(
        wob, 0, 512, Ot, hs, 512, bo, nullptr, x, hs, nullptr, out, hs, 4096, 512);
}